// Round 3
// baseline (144.883 us; speedup 1.0000x reference)
//
#include <hip/hip_runtime.h>

typedef __attribute__((ext_vector_type(4))) float f32x4;
typedef __attribute__((ext_vector_type(8))) short bf16x8;

__device__ __forceinline__ short f2bf(float f) {
    union { float f; unsigned u; } v; v.f = f;
    unsigned u = v.u;
    u += 0x7FFFu + ((u >> 16) & 1u);   // RNE
    return (short)(u >> 16);
}

// pack two fp32 -> two bf16 (round half-up) in one int via v_perm_b32
__device__ __forceinline__ int pack_bf2(float a, float b) {
    union { float f; unsigned u; } ua, ub; ua.f = a; ub.f = b;
    unsigned x = ua.u + 0x8000u, y = ub.u + 0x8000u;
    return (int)__builtin_amdgcn_perm(y, x, 0x07060302u);  // hi16=y>>16, lo16=x>>16
}

// ---------------------------------------------------------------------------
// Prep (grid 16 x 256): per component c
//   AbP[c][p][k]  = bf16(A_c[pi(p), k])   row-permuted for MFMA A-operand
//   Bneg2[c][k]   = bf16(-2 (A_c m_c)[k]) (original k order, bias-MFMA rows)
//   kscal[c]      = m^T A m
// ---------------------------------------------------------------------------
__global__ void gmm_prep(const float* __restrict__ Ainv,
                         const float* __restrict__ means,
                         short* __restrict__ AbP,
                         short* __restrict__ Bneg2,
                         float* __restrict__ kscal) {
    __shared__ float sA[64 * 68];
    __shared__ float sm[64];
    __shared__ float sb[64];
    const int c = blockIdx.x, t = threadIdx.x;
    const float* A = Ainv + c * 4096;
    #pragma unroll
    for (int i = 0; i < 4; ++i) {               // coalesced stage A -> LDS (padded)
        int flat = i * 1024 + t * 4;
        int r = flat >> 6, col = flat & 63;
        *(f32x4*)&sA[r * 68 + col] = *(const f32x4*)(A + flat);
    }
    if (t < 64) sm[t] = means[c * 64 + t];
    __syncthreads();
    {   // b[j] = A[j,:] . m   (4 lanes per row)
        int j = t >> 2, seg = t & 3;
        float p = 0.f;
        #pragma unroll
        for (int k = 0; k < 16; ++k) p += sA[j * 68 + seg * 16 + k] * sm[seg * 16 + k];
        p += __shfl_xor(p, 1, 64); p += __shfl_xor(p, 2, 64);
        if ((t & 3) == 0) sb[j] = p;
    }
    __syncthreads();
    if (t < 64) {                               // wave 0: kscal + Bneg2
        float km = sm[t] * sb[t];
        #pragma unroll
        for (int off = 32; off >= 1; off >>= 1) km += __shfl_xor(km, off, 64);
        if (t == 0) kscal[c] = km;
        Bneg2[c * 64 + t] = f2bf(-2.f * sb[t]);
    }
    {   // permuted bf16 A rows
        int p_ = t >> 2, kq = (t & 3) * 16;
        int rt = p_ >> 4, qh = (p_ >> 2) & 3, r = p_ & 3;
        int pj = (rt >> 1) * 32 + 8 * qh + 4 * (rt & 1) + r;
        bf16x8 v0, v1;
        #pragma unroll
        for (int i = 0; i < 8; ++i) {
            v0[i] = f2bf(sA[pj * 68 + kq + i]);
            v1[i] = f2bf(sA[pj * 68 + kq + 8 + i]);
        }
        *(bf16x8*)(AbP + c * 4096 + p_ * 64 + kq)     = v0;
        *(bf16x8*)(AbP + c * 4096 + p_ * 64 + kq + 8) = v1;
    }
}

// ---------------------------------------------------------------------------
// Main (grid N/512 x 256): 4 waves/block; wave w owns comps 4w..4w+3 with A
// permanently in registers (128 VGPRs). All waves stream the same 16-sample
// tiles global->reg (L1-shared). Bias term via one extra MFMA (rows 0..3 =
// -2 b_c). LDS only for the 4-way log-partial combine every 8 tiles.
// ---------------------------------------------------------------------------
__global__ __launch_bounds__(256, 2) void gmm_main(
    const float* __restrict__ X,
    const float* __restrict__ weights,
    const short* __restrict__ AbP,
    const short* __restrict__ Bneg2,
    const float* __restrict__ kscal,
    float* __restrict__ out) {

    __shared__ float sPart[8 * 4 * 16];   // [tile&7][wave][sample] 2 KB

    const int tid = threadIdx.x;
    const int lane = tid & 63, w = tid >> 6;
    const int q = lane >> 4, ln = lane & 15;

    // ---- persistent per-wave fragments ----
    bf16x8 af[4][4][2];                   // [c4][rt][kc]
    const short* Aw = AbP + (w * 4) * 4096 + ln * 64 + q * 8;
    #pragma unroll
    for (int c4 = 0; c4 < 4; ++c4)
        #pragma unroll
        for (int rt = 0; rt < 4; ++rt)
            #pragma unroll
            for (int kc = 0; kc < 2; ++kc)
                af[c4][rt][kc] = *(const bf16x8*)(Aw + c4 * 4096 + rt * 1024 + kc * 32);

    bf16x8 ab[2];
    {
        bf16x8 z;
        #pragma unroll
        for (int i = 0; i < 8; ++i) z[i] = 0;
        ab[0] = z; ab[1] = z;
        if (ln < 4) {
            ab[0] = *(const bf16x8*)(Bneg2 + (w * 4 + ln) * 64 + q * 8);
            ab[1] = *(const bf16x8*)(Bneg2 + (w * 4 + ln) * 64 + 32 + q * 8);
        }
    }
    float kw[4], wc[4];
    #pragma unroll
    for (int c4 = 0; c4 < 4; ++c4) { kw[c4] = kscal[w * 4 + c4]; wc[c4] = weights[w * 4 + c4]; }

    // ---- sample stream ----
    const int base = blockIdx.x * 512;
    const float* xp = X + (size_t)(base + ln) * 64 + q * 8;
    f32x4 xc[2][2];
    #pragma unroll
    for (int kc = 0; kc < 2; ++kc) {
        xc[kc][0] = *(const f32x4*)(xp + kc * 32);
        xc[kc][1] = *(const f32x4*)(xp + kc * 32 + 4);
    }

    const f32x4 zero4 = {0.f, 0.f, 0.f, 0.f};

    #pragma unroll 1
    for (int t = 0; t < 32; ++t) {
        const float* xnp = xp + 1024;
        f32x4 xn[2][2];
        if (t < 31) {                     // prefetch next tile
            #pragma unroll
            for (int kc = 0; kc < 2; ++kc) {
                xn[kc][0] = *(const f32x4*)(xnp + kc * 32);
                xn[kc][1] = *(const f32x4*)(xnp + kc * 32 + 4);
            }
        }

        // bf16 B-fragments from current tile
        bf16x8 bfr[2];
        #pragma unroll
        for (int kc = 0; kc < 2; ++kc) {
            union { int i[4]; bf16x8 v; } u;
            u.i[0] = pack_bf2(xc[kc][0][0], xc[kc][0][1]);
            u.i[1] = pack_bf2(xc[kc][0][2], xc[kc][0][3]);
            u.i[2] = pack_bf2(xc[kc][1][0], xc[kc][1][1]);
            u.i[3] = pack_bf2(xc[kc][1][2], xc[kc][1][3]);
            bfr[kc] = u.v;
        }

        // bias dots: rows 0..3 = comps (valid in q==0 lanes' regs)
        f32x4 bacc = __builtin_amdgcn_mfma_f32_16x16x32_bf16(ab[0], bfr[0], zero4, 0, 0, 0);
        bacc = __builtin_amdgcn_mfma_f32_16x16x32_bf16(ab[1], bfr[1], bacc, 0, 0, 0);

        float slog = 0.f;
        #pragma unroll
        for (int c4 = 0; c4 < 4; ++c4) {
            float dp = 0.f;
            #pragma unroll
            for (int rt = 0; rt < 4; ++rt) {
                f32x4 acc = __builtin_amdgcn_mfma_f32_16x16x32_bf16(
                    af[c4][rt][0], bfr[0], zero4, 0, 0, 0);
                acc = __builtin_amdgcn_mfma_f32_16x16x32_bf16(
                    af[c4][rt][1], bfr[1], acc, 0, 0, 0);
                f32x4 xm = xc[rt >> 1][rt & 1];   // fp32 x[n, pi(p)]
                dp += acc[0] * xm[0] + acc[1] * xm[1]
                    + acc[2] * xm[2] + acc[3] * xm[3];
            }
            dp += __shfl_xor(dp, 16, 64);
            dp += __shfl_xor(dp, 32, 64);
            if (q == 0) {
                float d = dp + bacc[c4] + kw[c4];
                d = fmaxf(d, 1e-30f);
                slog += wc[c4] * __builtin_amdgcn_logf(d);   // v_log_f32 = log2
            }
        }
        if (q == 0) sPart[(t & 7) * 64 + w * 16 + ln] = slog;

        if ((t & 7) == 7) {               // combine 128 samples
            __syncthreads();
            if (tid < 128) {
                int s = tid, o = (s >> 4) * 64 + (s & 15);
                float v = sPart[o] + sPart[o + 16] + sPart[o + 32] + sPart[o + 48];
                out[base + (t >> 3) * 128 + s] = __builtin_amdgcn_exp2f(v);
            }
            __syncthreads();
        }

        xp = xnp;
        #pragma unroll
        for (int kc = 0; kc < 2; ++kc) { xc[kc][0] = xn[kc][0]; xc[kc][1] = xn[kc][1]; }
    }
}

extern "C" void kernel_launch(void* const* d_in, const int* in_sizes, int n_in,
                              void* d_out, int out_size, void* d_ws, size_t ws_size,
                              hipStream_t stream) {
    const float* X       = (const float*)d_in[0];
    const float* Ainv    = (const float*)d_in[1];
    const float* means   = (const float*)d_in[2];
    const float* weights = (const float*)d_in[3];
    float* out = (float*)d_out;
    const int N = in_sizes[0] / 64;

    short* AbP   = (short*)d_ws;                       // 131072 B
    short* Bneg2 = (short*)((char*)d_ws + 131072);     // 2048 B
    float* kscal = (float*)((char*)d_ws + 133120);     // 64 B

    gmm_prep<<<dim3(16), dim3(256), 0, stream>>>(Ainv, means, AbP, Bneg2, kscal);
    gmm_main<<<dim3(N / 512), dim3(256), 0, stream>>>(X, weights, AbP, Bneg2, kscal, out);
}